// Round 8
// baseline (126.187 us; speedup 1.0000x reference)
//
#include <hip/hip_runtime.h>
#include <math.h>

// PostProcess: B=16, Q=2048, C=2. R8: three stream-ordered kernels, footprint
// restored to R6's PROVEN 1,147,904 B (R7 exceeded it by 32KB -- prime suspect
// for the failure; we ignore ws_size so never exceed a proven footprint).
//   kprep  (grid B*16 x 1024): verbatim R6 (compact + sort + matrix + M/sidxl).
//   kscan  (grid B x 64, LAUNCHED TWICE -- idempotent): R6-verified scan core;
//          keep decisions stored as BIT 15 of wsidx (qi uses 11 bits; kprep
//          rewrites wsidx fresh each call, clearing old flags). R7's never-
//          verified km-archival + shfl scatter is DELETED.
//   kepi   (grid B*2 x 1024): rebuilds per-q keep map in LDS from wsidx bit15
//          (guarded s < M; padding slots have bit15 set but are excluded),
//          then verbatim R6 epilogue. Fallback (M>NS, ~never) self-contained.
// Double kscan is deliberate instrumentation: dur ~= 54.5 + kprep + 2*scan +
// kepi, and with R6's sum (47.2) this yields scan duration X ~= dur - 103.
// ws: M u32[16]@0 | sidxl u16[16][1024]@1024 | mat u32[16][17408]@33792

#define QN     2048
#define NS     1024      // fast-path max valid boxes (E[M]=562, sd~20; M>NS ~23 sigma)
#define NSLICE 16
#define MATW   17408     // ragged u32 words/image = 64 * sum_{wb<16}(32-2wb)
#define WSIDX  1024      // byte offset of sidxl in ws
#define WSMAT  33792     // byte offset of matrix in ws

__device__ __forceinline__ int rb32(int wb) { return 64 * wb * (33 - wb); }

__device__ __forceinline__ unsigned long long shfl_xor_u64(unsigned long long x, int m) {
    int lo = __shfl_xor((int)(unsigned)(x & 0xffffffffull), m, 64);
    int hi = __shfl_xor((int)(unsigned)(x >> 32), m, 64);
    return ((unsigned long long)(unsigned)hi << 32) | (unsigned)lo;
}

// ascending key order == score desc, idx asc (stable); invalid -> tail.
__device__ __forceinline__ unsigned long long score_key(float2 l, int q, bool* valid_out) {
    float mx = fmaxf(l.x, l.y), mn = fminf(l.x, l.y);
    float e = expf(mn - mx);
    float score = 1.0f / (1.0f + e);                 // max softmax prob (exact ref order)
    bool valid = (l.x >= l.y) && (score >= 0.7f);    // argmax tie -> class 0
    *valid_out = valid;
    unsigned sbits = valid ? __float_as_uint(score) : 0u;
    return ((unsigned long long)(~sbits) << 32) | (unsigned)q;
}

// ================= kernel 1: compact + sort + matrix (verbatim R6) =============
__global__ __launch_bounds__(1024) void kprep(
    const float* __restrict__ logits, const float* __restrict__ pboxes,
    const int* __restrict__ img_h_p, const int* __restrict__ img_w_p,
    unsigned* __restrict__ wsM, unsigned short* __restrict__ wsidx,
    unsigned* __restrict__ wmat, int B)
{
    // skey u64[NS]@0 | sx1@8192 sy1@12288 sx2@16384 sy2@20480 sar@24576
    // | sM@32896 | skeyB u64[NS]@33024 (ping-pong exchange)
    __shared__ __align__(16) char smem[41216];
    unsigned long long* skey = (unsigned long long*)smem;
    float* sx1 = (float*)(smem + 8192);
    float* sy1 = (float*)(smem + 12288);
    float* sx2 = (float*)(smem + 16384);
    float* sy2 = (float*)(smem + 20480);
    float* sar = (float*)(smem + 24576);
    int* sMp = (int*)(smem + 32896);
    unsigned long long* skeyB = (unsigned long long*)(smem + 33024);

    const int blk = blockIdx.x;
    const int b = blk % B, slice = blk / B;
    const int tid = threadIdx.x, lane = tid & 63, wave = tid >> 6;
    const float sw = (float)(*img_w_p), sh = (float)(*img_h_p);

    if (tid == 0) *sMp = 0;
    __syncthreads();

    // ---- compact valid keys (ballot compaction; verified R4-R7) ----
    const unsigned long long lmask_lt = (1ull << lane) - 1ull;
#pragma unroll
    for (int qq = 0; qq < 2; ++qq) {
        int q = tid + qq * 1024;
        float2 l = ((const float2*)logits)[b * QN + q];
        bool valid;
        unsigned long long key = score_key(l, q, &valid);
        unsigned long long mb = __ballot(valid);
        int base = 0;
        if (lane == 0 && mb) base = atomicAdd(sMp, __popcll(mb));
        base = __shfl(base, 0, 64);
        if (valid) {
            int slot = base + __popcll(mb & lmask_lt);
            if (slot < NS) skey[slot] = key;
        }
    }
    __syncthreads();
    const int M = *sMp;
    if (slice == 0 && tid == 0) wsM[b] = (unsigned)M;

    if (M > NS) return;   // kepi handles the fallback end-to-end

    // ---- register bitonic sort of NS u64, 1 elem/thread (verified R4/R5) ----
    unsigned long long v = (tid < M) ? skey[tid] : ~0ull;
    __syncthreads();   // skey reused as exchange buffer
#pragma unroll
    for (int k = 2; k <= 64; k <<= 1) {
        bool dir = ((tid & k) == 0);
#pragma unroll
        for (int j = k >> 1; j > 0; j >>= 1) {
            unsigned long long o = shfl_xor_u64(v, j);
            bool takeMin = (dir == ((tid & j) == 0));
            v = ((v < o) == takeMin) ? v : o;
        }
    }
    int pp = 0;
    for (int k = 128; k <= NS; k <<= 1) {
        bool dir = ((tid & k) == 0);
        for (int j = k >> 1; j >= 64; j >>= 1) {
            unsigned long long* buf = pp ? skeyB : skey;
            pp ^= 1;
            buf[tid] = v;
            __syncthreads();
            unsigned long long o = buf[tid ^ j];
            bool takeMin = (dir == ((tid & j) == 0));
            v = ((v < o) == takeMin) ? v : o;
        }
#pragma unroll
        for (int j = 32; j > 0; j >>= 1) {
            unsigned long long o = shfl_xor_u64(v, j);
            bool takeMin = (dir == ((tid & j) == 0));
            v = ((v < o) == takeMin) ? v : o;
        }
    }
    // sorted SoA (padding slots zero -> iou 0); wsidx fresh write clears bit15
    int qi = (int)((unsigned)v & 0xffffu);
    if (slice == 0) wsidx[b * NS + tid] = (unsigned short)qi;
    float x1 = 0.f, y1 = 0.f, x2 = 0.f, y2 = 0.f, ar = 0.f;
    if (tid < M) {
        float4 pb = ((const float4*)pboxes)[b * QN + qi];
        x1 = (pb.x - 0.5f * pb.z) * sw;
        y1 = (pb.y - 0.5f * pb.w) * sh;
        x2 = (pb.x + 0.5f * pb.z) * sw;
        y2 = (pb.y + 0.5f * pb.w) * sh;
        ar = fmaxf(x2 - x1, 0.f) * fmaxf(y2 - y1, 0.f);
    }
    sx1[tid] = x1; sy1[tid] = y1; sx2[tid] = x2; sy2[tid] = y2; sar[tid] = ar;
    __syncthreads();

    // ---- matrix slice (verified R5-R7; 16 slices, stride 256) ----
    unsigned* mat = wmat + (long)b * MATW;
    const int NG = (M + 3) >> 2;
    const int W64 = (M + 63) >> 6;
    for (int gi = slice * 16 + wave; gi < NG; gi += 256) {
        const int g = gi << 2;
        const int nr = min(4, M - g);
        const int wb = g >> 6;
        const int rl = 32 - 2 * wb;
        float ax1[4], ay1[4], ax2[4], ay2[4], aar[4];
        int rbase[4];
#pragma unroll
        for (int r = 0; r < 4; ++r) {
            int i = g + min(r, nr - 1);
            ax1[r] = sx1[i]; ay1[r] = sy1[i];
            ax2[r] = sx2[i]; ay2[r] = sy2[i]; aar[r] = sar[i];
            rbase[r] = rb32(wb) + ((g + r) & 63) * rl;
        }
        for (int w = wb; w < W64; ++w) {
            int j = (w << 6) | lane;
            float bx1 = sx1[j], by1 = sy1[j], bx2 = sx2[j], by2 = sy2[j], bar = sar[j];
#pragma unroll
            for (int r = 0; r < 4; ++r) {
                float ltx = fmaxf(ax1[r], bx1), lty = fmaxf(ay1[r], by1);
                float rbx = fminf(ax2[r], bx2), rby = fminf(ay2[r], by2);
                float wx = fmaxf(rbx - ltx, 0.f), wy = fmaxf(rby - lty, 0.f);
                float inter = wx * wy;
                float uni = aar[r] + bar - inter;       // exact ref op order
                float iou = inter / fmaxf(uni, 1e-9f);  // exact IEEE div
                bool sup = (iou > 0.5f) && (j > g + r);
                unsigned long long bal = __ballot(sup);
                if (lane == 0 && r < nr)
                    *(unsigned long long*)(mat + rbase[r] + 2 * (w - wb)) = bal;
            }
        }
    }
    // plain stores; visibility downstream guaranteed at kernel boundary
}

// ============ kernel 2: single-wave greedy scan -> bit15 of wsidx ============
__global__ __launch_bounds__(64) void kscan(
    const unsigned* __restrict__ wsM, unsigned short* __restrict__ wsidx,
    const unsigned* __restrict__ wmat, int B)
{
    const int b = blockIdx.x;
    const int tid = threadIdx.x;
    const int M = (int)wsM[b];
    if (M > NS) return;   // fallback handled in kepi

    const unsigned* gm = wmat + (long)b * MATW;
    unsigned rem = 0;
    const int Ms = __builtin_amdgcn_readfirstlane(M);
    const int C = (Ms + 31) >> 5;
    const int lam = min(tid, 31);
    unsigned diag = 0, diagN = 0;
    unsigned rcur[32], rnxt[32];
    if (C > 0) {
#pragma unroll
        for (int t = 0; t < 32; ++t) rcur[t] = gm[lam + t * 32];
        diag = gm[lam * 32];           // c=0: wb=0, rl=32, word 0 of row lam
    }
    for (int c = 0; c < C; ++c) {
        if (c + 1 < C) {
            int cn = c + 1, wbn = cn >> 1, rln = 32 - 2 * wbn;
            int Lcn = min(max(tid, 2 * wbn), 31);
            int rb0n = rb32(wbn) + ((cn & 1) << 5) * rln + (Lcn - 2 * wbn);
#pragma unroll
            for (int t = 0; t < 32; ++t) rnxt[t] = gm[rb0n + t * rln];
            // diag for chunk cn: row 32*cn+lam, word index cn-2*wbn
            diagN = gm[rb32(wbn) + (((cn & 1) << 5) + lam) * rln + (cn - 2 * wbn)];
        }
        unsigned rw = (unsigned)__builtin_amdgcn_readlane((int)rem, c);
        int lim = min(32, Ms - (c << 5));
        unsigned limmask = (lim >= 32) ? 0xFFFFFFFFu : ((1u << lim) - 1u);
        unsigned avail = (~rw) & limmask;
        unsigned keepmask = 0;
        while (avail) {
            int t = __builtin_ctz(avail);
            keepmask |= (1u << t);
            unsigned rword = (unsigned)__builtin_amdgcn_readlane((int)diag, t);
            avail &= ~(1u << t);
            avail &= ~rword;
        }
        // merge kept rows into rem (branchless; same final rem by OR-comm.)
#pragma unroll
        for (int t = 0; t < 32; ++t)
            rem |= (0u - ((keepmask >> t) & 1u)) & rcur[t];
        // scatter this chunk's keeps: lane t flags sorted slot 32c+t
        if (tid < lim && ((keepmask >> tid) & 1u))
            wsidx[b * NS + (c << 5) + tid] |= 0x8000u;
        if (c + 1 < C) {
#pragma unroll
            for (int t = 0; t < 32; ++t) rcur[t] = rnxt[t];
            diag = diagN;
        }
    }
}

// ================= kernel 3: epilogue (1 q per thread) =================
__global__ __launch_bounds__(1024) void kepi(
    const float* __restrict__ logits, const float* __restrict__ pboxes,
    const int* __restrict__ img_h_p, const int* __restrict__ img_w_p,
    const unsigned* __restrict__ wsM, const unsigned short* __restrict__ wsidx,
    float* __restrict__ out, int B)
{
    // fast path: keepq u8[QN]@0. fallback overlays: skeyF u64[QN]@0 (16KB) |
    // ssupp u8[QN]@16384 | keepqF u8[QN]@18432
    __shared__ __align__(16) char smem[20480];
    unsigned char* keepq = (unsigned char*)smem;

    const int blk = blockIdx.x;
    const int b = blk >> 1, half = blk & 1;
    const int tid = threadIdx.x;
    const int q = half * 1024 + tid;
    const float sw = (float)(*img_w_p), sh = (float)(*img_h_p);
    const int M = (int)wsM[b];

    int kp;
    if (M <= NS) {
        keepq[tid] = 0; keepq[tid + 1024] = 0;
        __syncthreads();
        // rebuild per-q keep map from wsidx bit15 (thread tid = sorted slot tid);
        // s < M guard excludes padding slots (whose qi=0xFFFF has bit15 set)
        unsigned e = wsidx[b * NS + tid];
        if (tid < M && (e & 0x8000u)) keepq[e & 0x7FFu] = 1;
        __syncthreads();
        kp = keepq[q];
    } else {
        // ---- Fallback (M > NS, ~never): self-contained LDS sort + greedy ----
        unsigned long long* skeyF = (unsigned long long*)smem;
        unsigned char* ssupp = (unsigned char*)(smem + 16384);
        unsigned char* keepqF = (unsigned char*)(smem + 18432);
        for (int qq = tid; qq < QN; qq += 1024) {
            float2 l = ((const float2*)logits)[b * QN + qq];
            bool valid;
            skeyF[qq] = score_key(l, qq, &valid);
        }
        keepqF[tid] = 0; keepqF[tid + 1024] = 0;
        __syncthreads();
        for (int k = 2; k <= QN; k <<= 1)
            for (int j = k >> 1; j > 0; j >>= 1) {
                int i = ((tid & ~(j - 1)) << 1) | (tid & (j - 1));
                int p = i | j;
                bool up = ((i & k) == 0);
                unsigned long long a = skeyF[i], c2 = skeyF[p];
                if ((a > c2) == up) { skeyF[i] = c2; skeyF[p] = a; }
                __syncthreads();
            }
        for (int s = tid; s < M; s += 1024) ssupp[s] = 0;
        __syncthreads();
        for (int i = 0; i < M; ++i) {
            __syncthreads();
            if (ssupp[i]) continue;
            int ia = (unsigned short)(unsigned)skeyF[i];
            float4 pa = ((const float4*)pboxes)[b * QN + ia];
            float ax1 = (pa.x - 0.5f * pa.z) * sw, ay1 = (pa.y - 0.5f * pa.w) * sh;
            float ax2 = (pa.x + 0.5f * pa.z) * sw, ay2 = (pa.y + 0.5f * pa.w) * sh;
            float areaA = fmaxf(ax2 - ax1, 0.f) * fmaxf(ay2 - ay1, 0.f);
            for (int jj = i + 1 + tid; jj < M; jj += 1024) {
                int jb = (unsigned short)(unsigned)skeyF[jj];
                float4 pq = ((const float4*)pboxes)[b * QN + jb];
                float bx1 = (pq.x - 0.5f * pq.z) * sw, by1 = (pq.y - 0.5f * pq.w) * sh;
                float bx2 = (pq.x + 0.5f * pq.z) * sw, by2 = (pq.y + 0.5f * pq.w) * sh;
                float ltx = fmaxf(ax1, bx1), lty = fmaxf(ay1, by1);
                float rbx = fminf(ax2, bx2), rby = fminf(ay2, by2);
                float wx = fmaxf(rbx - ltx, 0.f), wy = fmaxf(rby - lty, 0.f);
                float inter = wx * wy;
                float areaB = fmaxf(bx2 - bx1, 0.f) * fmaxf(by2 - by1, 0.f);
                float uni = areaA + areaB - inter;
                if (inter / fmaxf(uni, 1e-9f) > 0.5f) ssupp[jj] = 1;
            }
        }
        __syncthreads();
        for (int s = tid; s < M; s += 1024)
            if (!ssupp[s]) keepqF[(unsigned short)(unsigned)skeyF[s]] = 1;
        __syncthreads();
        kp = keepqF[q];
    }

    // ---- epilogue: all outputs (d_out poisoned every call) ----
    const long BQ = (long)B * QN;
    int base = b * QN + q;
    float2 l = ((const float2*)logits)[base];
    float e = expf(fminf(l.x, l.y) - fmaxf(l.x, l.y));
    float score = 1.0f / (1.0f + e);
    float4 pb = ((const float4*)pboxes)[base];
    float x1 = (pb.x - 0.5f * pb.z) * sw, y1 = (pb.y - 0.5f * pb.w) * sh;
    float x2 = (pb.x + 0.5f * pb.z) * sw, y2 = (pb.y + 0.5f * pb.w) * sh;
    out[base] = kp ? score : 0.f;
    out[BQ * 5 + base] = kp ? 1.f : 0.f;
    float4 ob;
    ob.x = kp ? truncf(x1) : 0.f;
    ob.y = kp ? truncf(y1) : 0.f;
    ob.z = kp ? truncf(x2) : 0.f;
    ob.w = kp ? truncf(y2) : 0.f;
    ((float4*)(out + BQ))[base] = ob;
}

extern "C" void kernel_launch(void* const* d_in, const int* in_sizes, int n_in,
                              void* d_out, int out_size, void* d_ws, size_t ws_size,
                              hipStream_t stream) {
    const float* logits = (const float*)d_in[0];
    const float* pboxes = (const float*)d_in[1];
    const int*   img_h  = (const int*)d_in[2];
    const int*   img_w  = (const int*)d_in[3];
    float* out = (float*)d_out;
    const int B = in_sizes[0] / (QN * 2);   // 16

    char* ws = (char*)d_ws;                 // footprint 1,147,904 B (= proven R6)
    unsigned*       wsM   = (unsigned*)(ws + 0);
    unsigned short* wsidx = (unsigned short*)(ws + WSIDX);
    unsigned*       wmat  = (unsigned*)(ws + WSMAT);

    kprep<<<dim3(B * NSLICE), dim3(1024), 0, stream>>>(logits, pboxes, img_h, img_w,
                                                       wsM, wsidx, wmat, B);
    // launched TWICE (idempotent) -- deliberate timing instrumentation:
    // dur ~= 54.5 + kprep + 2*kscan + kepi; R6 gives kscan = dur - ~103.
    kscan<<<dim3(B), dim3(64), 0, stream>>>(wsM, wsidx, wmat, B);
    kscan<<<dim3(B), dim3(64), 0, stream>>>(wsM, wsidx, wmat, B);
    kepi<<<dim3(B * 2), dim3(1024), 0, stream>>>(logits, pboxes, img_h, img_w,
                                                 wsM, wsidx, out, B);
}

// Round 9
// 98.772 us; speedup vs baseline: 1.2776x; 1.2776x over previous
//
#include <hip/hip_runtime.h>
#include <math.h>

// PostProcess: B=16, Q=2048, C=2. R9: TWO stream-ordered kernels.
// R8's double-kscan instrumentation convicted the single-wave scan: ~22us of
// the ~47us controllable budget, dominated by per-chunk global-load latency
// (wmat written by 256 blocks across 8 XCDs -> reader L2-misses; 18 serial
// chunks x ~1000cy at the low DVFS clock these tiny kernels run at).
//   kprep  (grid B*16 x 1024): verbatim R8 (passed) -- compact + sort + matrix.
//   kfinal (grid B x 1024): NEW staging: cooperative vec4 copy of the image's
//          matrix into LDS (~2us, bulk-coalesced), THEN the verified ff1 scan
//          reads LDS (ds_read ~120cy, hidden under ~400cy/chunk compute).
//          Epilogue input loads hoisted into registers before the barrier
//          (latency hides under copy+scan). Scan logic, scatter, fallback,
//          epilogue formulas verbatim from verified rounds.
// ws: M u32[16]@0 | sidxl u16[16][1024]@1024 | mat u32[16][17408]@33792
//     (footprint 1,147,904 B = proven R6/R8)

#define QN     2048
#define NS     1024      // fast-path max valid boxes (E[M]=562, sd~20; M>NS ~23 sigma)
#define NSLICE 16
#define MATW   17408     // ragged u32 words/image = 64 * sum_{wb<16}(32-2wb)
#define WSIDX  1024      // byte offset of sidxl in ws
#define WSMAT  33792     // byte offset of matrix in ws

__device__ __forceinline__ int rb32(int wb) { return 64 * wb * (33 - wb); }

__device__ __forceinline__ unsigned long long shfl_xor_u64(unsigned long long x, int m) {
    int lo = __shfl_xor((int)(unsigned)(x & 0xffffffffull), m, 64);
    int hi = __shfl_xor((int)(unsigned)(x >> 32), m, 64);
    return ((unsigned long long)(unsigned)hi << 32) | (unsigned)lo;
}

// ascending key order == score desc, idx asc (stable); invalid -> tail.
__device__ __forceinline__ unsigned long long score_key(float2 l, int q, bool* valid_out) {
    float mx = fmaxf(l.x, l.y), mn = fminf(l.x, l.y);
    float e = expf(mn - mx);
    float score = 1.0f / (1.0f + e);                 // max softmax prob (exact ref order)
    bool valid = (l.x >= l.y) && (score >= 0.7f);    // argmax tie -> class 0
    *valid_out = valid;
    unsigned sbits = valid ? __float_as_uint(score) : 0u;
    return ((unsigned long long)(~sbits) << 32) | (unsigned)q;
}

// ================= kernel 1: compact + sort + matrix (verbatim R8) =============
__global__ __launch_bounds__(1024) void kprep(
    const float* __restrict__ logits, const float* __restrict__ pboxes,
    const int* __restrict__ img_h_p, const int* __restrict__ img_w_p,
    unsigned* __restrict__ wsM, unsigned short* __restrict__ wsidx,
    unsigned* __restrict__ wmat, int B)
{
    // skey u64[NS]@0 | sx1@8192 sy1@12288 sx2@16384 sy2@20480 sar@24576
    // | sM@32896 | skeyB u64[NS]@33024 (ping-pong exchange)
    __shared__ __align__(16) char smem[41216];
    unsigned long long* skey = (unsigned long long*)smem;
    float* sx1 = (float*)(smem + 8192);
    float* sy1 = (float*)(smem + 12288);
    float* sx2 = (float*)(smem + 16384);
    float* sy2 = (float*)(smem + 20480);
    float* sar = (float*)(smem + 24576);
    int* sMp = (int*)(smem + 32896);
    unsigned long long* skeyB = (unsigned long long*)(smem + 33024);

    const int blk = blockIdx.x;
    const int b = blk % B, slice = blk / B;
    const int tid = threadIdx.x, lane = tid & 63, wave = tid >> 6;
    const float sw = (float)(*img_w_p), sh = (float)(*img_h_p);

    if (tid == 0) *sMp = 0;
    __syncthreads();

    // ---- compact valid keys (ballot compaction; verified R4-R7) ----
    const unsigned long long lmask_lt = (1ull << lane) - 1ull;
#pragma unroll
    for (int qq = 0; qq < 2; ++qq) {
        int q = tid + qq * 1024;
        float2 l = ((const float2*)logits)[b * QN + q];
        bool valid;
        unsigned long long key = score_key(l, q, &valid);
        unsigned long long mb = __ballot(valid);
        int base = 0;
        if (lane == 0 && mb) base = atomicAdd(sMp, __popcll(mb));
        base = __shfl(base, 0, 64);
        if (valid) {
            int slot = base + __popcll(mb & lmask_lt);
            if (slot < NS) skey[slot] = key;
        }
    }
    __syncthreads();
    const int M = *sMp;
    if (slice == 0 && tid == 0) wsM[b] = (unsigned)M;

    if (M > NS) return;   // kfinal handles the fallback end-to-end

    // ---- register bitonic sort of NS u64, 1 elem/thread (verified R4/R5) ----
    unsigned long long v = (tid < M) ? skey[tid] : ~0ull;
    __syncthreads();   // skey reused as exchange buffer
#pragma unroll
    for (int k = 2; k <= 64; k <<= 1) {
        bool dir = ((tid & k) == 0);
#pragma unroll
        for (int j = k >> 1; j > 0; j >>= 1) {
            unsigned long long o = shfl_xor_u64(v, j);
            bool takeMin = (dir == ((tid & j) == 0));
            v = ((v < o) == takeMin) ? v : o;
        }
    }
    int pp = 0;
    for (int k = 128; k <= NS; k <<= 1) {
        bool dir = ((tid & k) == 0);
        for (int j = k >> 1; j >= 64; j >>= 1) {
            unsigned long long* buf = pp ? skeyB : skey;
            pp ^= 1;
            buf[tid] = v;
            __syncthreads();
            unsigned long long o = buf[tid ^ j];
            bool takeMin = (dir == ((tid & j) == 0));
            v = ((v < o) == takeMin) ? v : o;
        }
#pragma unroll
        for (int j = 32; j > 0; j >>= 1) {
            unsigned long long o = shfl_xor_u64(v, j);
            bool takeMin = (dir == ((tid & j) == 0));
            v = ((v < o) == takeMin) ? v : o;
        }
    }
    // sorted SoA (padding slots zero -> iou 0)
    int qi = (int)((unsigned)v & 0xffffu);
    if (slice == 0) wsidx[b * NS + tid] = (unsigned short)qi;
    float x1 = 0.f, y1 = 0.f, x2 = 0.f, y2 = 0.f, ar = 0.f;
    if (tid < M) {
        float4 pb = ((const float4*)pboxes)[b * QN + qi];
        x1 = (pb.x - 0.5f * pb.z) * sw;
        y1 = (pb.y - 0.5f * pb.w) * sh;
        x2 = (pb.x + 0.5f * pb.z) * sw;
        y2 = (pb.y + 0.5f * pb.w) * sh;
        ar = fmaxf(x2 - x1, 0.f) * fmaxf(y2 - y1, 0.f);
    }
    sx1[tid] = x1; sy1[tid] = y1; sx2[tid] = x2; sy2[tid] = y2; sar[tid] = ar;
    __syncthreads();

    // ---- matrix slice (verified R5-R8; 16 slices, stride 256) ----
    unsigned* mat = wmat + (long)b * MATW;
    const int NG = (M + 3) >> 2;
    const int W64 = (M + 63) >> 6;
    for (int gi = slice * 16 + wave; gi < NG; gi += 256) {
        const int g = gi << 2;
        const int nr = min(4, M - g);
        const int wb = g >> 6;
        const int rl = 32 - 2 * wb;
        float ax1[4], ay1[4], ax2[4], ay2[4], aar[4];
        int rbase[4];
#pragma unroll
        for (int r = 0; r < 4; ++r) {
            int i = g + min(r, nr - 1);
            ax1[r] = sx1[i]; ay1[r] = sy1[i];
            ax2[r] = sx2[i]; ay2[r] = sy2[i]; aar[r] = sar[i];
            rbase[r] = rb32(wb) + ((g + r) & 63) * rl;
        }
        for (int w = wb; w < W64; ++w) {
            int j = (w << 6) | lane;
            float bx1 = sx1[j], by1 = sy1[j], bx2 = sx2[j], by2 = sy2[j], bar = sar[j];
#pragma unroll
            for (int r = 0; r < 4; ++r) {
                float ltx = fmaxf(ax1[r], bx1), lty = fmaxf(ay1[r], by1);
                float rbx = fminf(ax2[r], bx2), rby = fminf(ay2[r], by2);
                float wx = fmaxf(rbx - ltx, 0.f), wy = fmaxf(rby - lty, 0.f);
                float inter = wx * wy;
                float uni = aar[r] + bar - inter;       // exact ref op order
                float iou = inter / fmaxf(uni, 1e-9f);  // exact IEEE div
                bool sup = (iou > 0.5f) && (j > g + r);
                unsigned long long bal = __ballot(sup);
                if (lane == 0 && r < nr)
                    *(unsigned long long*)(mat + rbase[r] + 2 * (w - wb)) = bal;
            }
        }
    }
    // plain stores; visibility downstream guaranteed at kernel boundary
}

// ========== kernel 2: LDS-staged scan + scatter + epilogue ==========
__global__ __launch_bounds__(1024) void kfinal(
    const float* __restrict__ logits, const float* __restrict__ pboxes,
    const int* __restrict__ img_h_p, const int* __restrict__ img_w_p,
    const unsigned* __restrict__ wsM, const unsigned short* __restrict__ wsidx,
    const unsigned* __restrict__ wmat, float* __restrict__ out, int B)
{
    // smat u32[MATW]@0 (69632 B) | sidxl u16[NS]@69632 | keepq u8[QN]@71680
    // | skm u32[32]@73728.  fallback overlays @0: skeyF u64[QN] (16KB) |
    // ssupp u8[QN]@16384 (keepq/sidxl/skm untouched by overlay).
    __shared__ __align__(16) char smem[73856];
    unsigned* smat = (unsigned*)smem;
    unsigned short* sidxl = (unsigned short*)(smem + 69632);
    unsigned char* keepq = (unsigned char*)(smem + 71680);
    unsigned* skm = (unsigned*)(smem + 73728);

    const int b = blockIdx.x;
    const int tid = threadIdx.x;
    const float sw = (float)(*img_w_p), sh = (float)(*img_h_p);
    const int M = (int)wsM[b];

    // hoisted epilogue inputs (registers; latency hides under copy+scan)
    float2 l0 = ((const float2*)logits)[b * QN + tid];
    float2 l1 = ((const float2*)logits)[b * QN + tid + 1024];
    float4 p0 = ((const float4*)pboxes)[b * QN + tid];
    float4 p1 = ((const float4*)pboxes)[b * QN + tid + 1024];

    keepq[tid] = 0; keepq[tid + 1024] = 0;
    if (tid < 32) skm[tid] = 0;

    if (M <= NS) {
        // ---- stage matrix (vec4 coalesced) + sidxl into LDS ----
        const int W64 = (M + 63) >> 6;
        const int nw4 = rb32(W64) >> 2;          // rb32 is divisible by 4
        const uint4* gm4 = (const uint4*)(wmat + (long)b * MATW);
        uint4* sm4 = (uint4*)smat;
        for (int i = tid; i < nw4; i += 1024) sm4[i] = gm4[i];
        sidxl[tid] = wsidx[b * NS + tid];
        __syncthreads();

        // ---- single-wave ff1 greedy scan (verbatim R8 core; gm := LDS) ----
        if (tid < 64) {
            const unsigned* gm = smat;
            unsigned rem = 0;
            const int Ms = __builtin_amdgcn_readfirstlane(M);
            const int C = (Ms + 31) >> 5;
            const int lam = min(tid, 31);
            unsigned diag = 0, diagN = 0;
            unsigned rcur[32], rnxt[32];
            if (C > 0) {
#pragma unroll
                for (int t = 0; t < 32; ++t) rcur[t] = gm[lam + t * 32];
                diag = gm[lam * 32];           // c=0: wb=0, rl=32, word 0 of row lam
            }
            for (int c = 0; c < C; ++c) {
                if (c + 1 < C) {
                    int cn = c + 1, wbn = cn >> 1, rln = 32 - 2 * wbn;
                    int Lcn = min(max(tid, 2 * wbn), 31);
                    int rb0n = rb32(wbn) + ((cn & 1) << 5) * rln + (Lcn - 2 * wbn);
#pragma unroll
                    for (int t = 0; t < 32; ++t) rnxt[t] = gm[rb0n + t * rln];
                    // diag for chunk cn: row 32*cn+lam, word index cn-2*wbn
                    diagN = gm[rb32(wbn) + (((cn & 1) << 5) + lam) * rln + (cn - 2 * wbn)];
                }
                unsigned rw = (unsigned)__builtin_amdgcn_readlane((int)rem, c);
                int lim = min(32, Ms - (c << 5));
                unsigned limmask = (lim >= 32) ? 0xFFFFFFFFu : ((1u << lim) - 1u);
                unsigned avail = (~rw) & limmask;
                unsigned keepmask = 0;
                while (avail) {
                    int t = __builtin_ctz(avail);
                    keepmask |= (1u << t);
                    unsigned rword = (unsigned)__builtin_amdgcn_readlane((int)diag, t);
                    avail &= ~(1u << t);
                    avail &= ~rword;
                }
                // merge kept rows into rem (branchless; same final rem by OR-comm.)
#pragma unroll
                for (int t = 0; t < 32; ++t)
                    rem |= (0u - ((keepmask >> t) & 1u)) & rcur[t];
                if (tid == 0) skm[c] = keepmask;
                if (c + 1 < C) {
#pragma unroll
                    for (int t = 0; t < 32; ++t) rcur[t] = rnxt[t];
                    diag = diagN;
                }
            }
        }
        __syncthreads();
        // ---- scatter (verified R6) ----
        for (int s = tid; s < M; s += 1024)
            if ((skm[s >> 5] >> (s & 31)) & 1u) keepq[sidxl[s]] = 1;
        __syncthreads();
    } else {
        // ---- Fallback (M > NS, ~never): self-contained LDS sort + greedy ----
        unsigned long long* skeyF = (unsigned long long*)smem;
        unsigned char* ssupp = (unsigned char*)(smem + 16384);
        __syncthreads();   // keepq zeroing visible before use below
        for (int qq = tid; qq < QN; qq += 1024) {
            float2 l = ((const float2*)logits)[b * QN + qq];
            bool valid;
            skeyF[qq] = score_key(l, qq, &valid);
        }
        __syncthreads();
        for (int k = 2; k <= QN; k <<= 1)
            for (int j = k >> 1; j > 0; j >>= 1) {
                int i = ((tid & ~(j - 1)) << 1) | (tid & (j - 1));
                int p = i | j;
                bool up = ((i & k) == 0);
                unsigned long long a = skeyF[i], c2 = skeyF[p];
                if ((a > c2) == up) { skeyF[i] = c2; skeyF[p] = a; }
                __syncthreads();
            }
        for (int s = tid; s < M; s += 1024) ssupp[s] = 0;
        __syncthreads();
        for (int i = 0; i < M; ++i) {
            __syncthreads();
            if (ssupp[i]) continue;
            int ia = (unsigned short)(unsigned)skeyF[i];
            float4 pa = ((const float4*)pboxes)[b * QN + ia];
            float ax1 = (pa.x - 0.5f * pa.z) * sw, ay1 = (pa.y - 0.5f * pa.w) * sh;
            float ax2 = (pa.x + 0.5f * pa.z) * sw, ay2 = (pa.y + 0.5f * pa.w) * sh;
            float areaA = fmaxf(ax2 - ax1, 0.f) * fmaxf(ay2 - ay1, 0.f);
            for (int jj = i + 1 + tid; jj < M; jj += 1024) {
                int jb = (unsigned short)(unsigned)skeyF[jj];
                float4 pq = ((const float4*)pboxes)[b * QN + jb];
                float bx1 = (pq.x - 0.5f * pq.z) * sw, by1 = (pq.y - 0.5f * pq.w) * sh;
                float bx2 = (pq.x + 0.5f * pq.z) * sw, by2 = (pq.y + 0.5f * pq.w) * sh;
                float ltx = fmaxf(ax1, bx1), lty = fmaxf(ay1, by1);
                float rbx = fminf(ax2, bx2), rby = fminf(ay2, by2);
                float wx = fmaxf(rbx - ltx, 0.f), wy = fmaxf(rby - lty, 0.f);
                float inter = wx * wy;
                float areaB = fmaxf(bx2 - bx1, 0.f) * fmaxf(by2 - by1, 0.f);
                float uni = areaA + areaB - inter;
                if (inter / fmaxf(uni, 1e-9f) > 0.5f) ssupp[jj] = 1;
            }
        }
        __syncthreads();
        for (int s = tid; s < M; s += 1024)
            if (!ssupp[s]) keepq[(unsigned short)(unsigned)skeyF[s]] = 1;
        __syncthreads();
    }

    // ---- epilogue from hoisted registers (formulas verbatim R6) ----
    const long BQ = (long)B * QN;
    {
        int base = b * QN + tid;
        float e = expf(fminf(l0.x, l0.y) - fmaxf(l0.x, l0.y));
        float score = 1.0f / (1.0f + e);
        float x1 = (p0.x - 0.5f * p0.z) * sw, y1 = (p0.y - 0.5f * p0.w) * sh;
        float x2 = (p0.x + 0.5f * p0.z) * sw, y2 = (p0.y + 0.5f * p0.w) * sh;
        int kp = keepq[tid];
        out[base] = kp ? score : 0.f;
        out[BQ * 5 + base] = kp ? 1.f : 0.f;
        float4 ob;
        ob.x = kp ? truncf(x1) : 0.f;
        ob.y = kp ? truncf(y1) : 0.f;
        ob.z = kp ? truncf(x2) : 0.f;
        ob.w = kp ? truncf(y2) : 0.f;
        ((float4*)(out + BQ))[base] = ob;
    }
    {
        int base = b * QN + tid + 1024;
        float e = expf(fminf(l1.x, l1.y) - fmaxf(l1.x, l1.y));
        float score = 1.0f / (1.0f + e);
        float x1 = (p1.x - 0.5f * p1.z) * sw, y1 = (p1.y - 0.5f * p1.w) * sh;
        float x2 = (p1.x + 0.5f * p1.z) * sw, y2 = (p1.y + 0.5f * p1.w) * sh;
        int kp = keepq[tid + 1024];
        out[base] = kp ? score : 0.f;
        out[BQ * 5 + base] = kp ? 1.f : 0.f;
        float4 ob;
        ob.x = kp ? truncf(x1) : 0.f;
        ob.y = kp ? truncf(y1) : 0.f;
        ob.z = kp ? truncf(x2) : 0.f;
        ob.w = kp ? truncf(y2) : 0.f;
        ((float4*)(out + BQ))[base] = ob;
    }
}

extern "C" void kernel_launch(void* const* d_in, const int* in_sizes, int n_in,
                              void* d_out, int out_size, void* d_ws, size_t ws_size,
                              hipStream_t stream) {
    const float* logits = (const float*)d_in[0];
    const float* pboxes = (const float*)d_in[1];
    const int*   img_h  = (const int*)d_in[2];
    const int*   img_w  = (const int*)d_in[3];
    float* out = (float*)d_out;
    const int B = in_sizes[0] / (QN * 2);   // 16

    char* ws = (char*)d_ws;                 // footprint 1,147,904 B (= proven R6/R8)
    unsigned*       wsM   = (unsigned*)(ws + 0);
    unsigned short* wsidx = (unsigned short*)(ws + WSIDX);
    unsigned*       wmat  = (unsigned*)(ws + WSMAT);

    kprep<<<dim3(B * NSLICE), dim3(1024), 0, stream>>>(logits, pboxes, img_h, img_w,
                                                       wsM, wsidx, wmat, B);
    kfinal<<<dim3(B), dim3(1024), 0, stream>>>(logits, pboxes, img_h, img_w,
                                               wsM, wsidx, wmat, out, B);
}

// Round 10
// 97.931 us; speedup vs baseline: 1.2885x; 1.0086x over previous
//
#include <hip/hip_runtime.h>
#include <math.h>

// PostProcess: B=16, Q=2048, C=2. R10 = R9 (98.8us, passing) + ONE change:
// the single-wave scan's inner loop is rewritten BRANCHLESS (fully unrolled,
// constant-lane readlane, wave-uniform rw/keepmask -> SALU chain) and the
// rcur<-rnxt prefetch double-buffer is dropped (rcur+diag loaded per chunk
// from LDS; deletes 64 v_movs/chunk, halves scan VGPRs). R8/R9 evidence:
// scan is serial-ISSUE-bound (~20us), not memory-bound -- the data-dependent
// while(avail) pop loop (readfirstlane+branch ~40-60cy x ~9/chunk) and the
// register copies are the cost. Semantics proven identical (see derivation:
// rw |= ~limmask pre-suppresses t>=lim; rword bits <= s are 0 by j>i
// triangularity so ascending-t processing is order-exact).
//   kprep  (grid B*16 x 1024): verbatim R8/R9 (passed).
//   kfinal (grid B x 1024): verbatim R9 except the scan core.
// ws: M u32[16]@0 | sidxl u16[16][1024]@1024 | mat u32[16][17408]@33792
//     (footprint 1,147,904 B = proven R6/R8/R9)

#define QN     2048
#define NS     1024      // fast-path max valid boxes (E[M]=562, sd~20; M>NS ~23 sigma)
#define NSLICE 16
#define MATW   17408     // ragged u32 words/image = 64 * sum_{wb<16}(32-2wb)
#define WSIDX  1024      // byte offset of sidxl in ws
#define WSMAT  33792     // byte offset of matrix in ws

__device__ __forceinline__ int rb32(int wb) { return 64 * wb * (33 - wb); }

__device__ __forceinline__ unsigned long long shfl_xor_u64(unsigned long long x, int m) {
    int lo = __shfl_xor((int)(unsigned)(x & 0xffffffffull), m, 64);
    int hi = __shfl_xor((int)(unsigned)(x >> 32), m, 64);
    return ((unsigned long long)(unsigned)hi << 32) | (unsigned)lo;
}

// ascending key order == score desc, idx asc (stable); invalid -> tail.
__device__ __forceinline__ unsigned long long score_key(float2 l, int q, bool* valid_out) {
    float mx = fmaxf(l.x, l.y), mn = fminf(l.x, l.y);
    float e = expf(mn - mx);
    float score = 1.0f / (1.0f + e);                 // max softmax prob (exact ref order)
    bool valid = (l.x >= l.y) && (score >= 0.7f);    // argmax tie -> class 0
    *valid_out = valid;
    unsigned sbits = valid ? __float_as_uint(score) : 0u;
    return ((unsigned long long)(~sbits) << 32) | (unsigned)q;
}

// ================= kernel 1: compact + sort + matrix (verbatim R8/R9) ==========
__global__ __launch_bounds__(1024) void kprep(
    const float* __restrict__ logits, const float* __restrict__ pboxes,
    const int* __restrict__ img_h_p, const int* __restrict__ img_w_p,
    unsigned* __restrict__ wsM, unsigned short* __restrict__ wsidx,
    unsigned* __restrict__ wmat, int B)
{
    // skey u64[NS]@0 | sx1@8192 sy1@12288 sx2@16384 sy2@20480 sar@24576
    // | sM@32896 | skeyB u64[NS]@33024 (ping-pong exchange)
    __shared__ __align__(16) char smem[41216];
    unsigned long long* skey = (unsigned long long*)smem;
    float* sx1 = (float*)(smem + 8192);
    float* sy1 = (float*)(smem + 12288);
    float* sx2 = (float*)(smem + 16384);
    float* sy2 = (float*)(smem + 20480);
    float* sar = (float*)(smem + 24576);
    int* sMp = (int*)(smem + 32896);
    unsigned long long* skeyB = (unsigned long long*)(smem + 33024);

    const int blk = blockIdx.x;
    const int b = blk % B, slice = blk / B;
    const int tid = threadIdx.x, lane = tid & 63, wave = tid >> 6;
    const float sw = (float)(*img_w_p), sh = (float)(*img_h_p);

    if (tid == 0) *sMp = 0;
    __syncthreads();

    // ---- compact valid keys (ballot compaction; verified R4-R9) ----
    const unsigned long long lmask_lt = (1ull << lane) - 1ull;
#pragma unroll
    for (int qq = 0; qq < 2; ++qq) {
        int q = tid + qq * 1024;
        float2 l = ((const float2*)logits)[b * QN + q];
        bool valid;
        unsigned long long key = score_key(l, q, &valid);
        unsigned long long mb = __ballot(valid);
        int base = 0;
        if (lane == 0 && mb) base = atomicAdd(sMp, __popcll(mb));
        base = __shfl(base, 0, 64);
        if (valid) {
            int slot = base + __popcll(mb & lmask_lt);
            if (slot < NS) skey[slot] = key;
        }
    }
    __syncthreads();
    const int M = *sMp;
    if (slice == 0 && tid == 0) wsM[b] = (unsigned)M;

    if (M > NS) return;   // kfinal handles the fallback end-to-end

    // ---- register bitonic sort of NS u64, 1 elem/thread (verified R4/R5) ----
    unsigned long long v = (tid < M) ? skey[tid] : ~0ull;
    __syncthreads();   // skey reused as exchange buffer
#pragma unroll
    for (int k = 2; k <= 64; k <<= 1) {
        bool dir = ((tid & k) == 0);
#pragma unroll
        for (int j = k >> 1; j > 0; j >>= 1) {
            unsigned long long o = shfl_xor_u64(v, j);
            bool takeMin = (dir == ((tid & j) == 0));
            v = ((v < o) == takeMin) ? v : o;
        }
    }
    int pp = 0;
    for (int k = 128; k <= NS; k <<= 1) {
        bool dir = ((tid & k) == 0);
        for (int j = k >> 1; j >= 64; j >>= 1) {
            unsigned long long* buf = pp ? skeyB : skey;
            pp ^= 1;
            buf[tid] = v;
            __syncthreads();
            unsigned long long o = buf[tid ^ j];
            bool takeMin = (dir == ((tid & j) == 0));
            v = ((v < o) == takeMin) ? v : o;
        }
#pragma unroll
        for (int j = 32; j > 0; j >>= 1) {
            unsigned long long o = shfl_xor_u64(v, j);
            bool takeMin = (dir == ((tid & j) == 0));
            v = ((v < o) == takeMin) ? v : o;
        }
    }
    // sorted SoA (padding slots zero -> iou 0)
    int qi = (int)((unsigned)v & 0xffffu);
    if (slice == 0) wsidx[b * NS + tid] = (unsigned short)qi;
    float x1 = 0.f, y1 = 0.f, x2 = 0.f, y2 = 0.f, ar = 0.f;
    if (tid < M) {
        float4 pb = ((const float4*)pboxes)[b * QN + qi];
        x1 = (pb.x - 0.5f * pb.z) * sw;
        y1 = (pb.y - 0.5f * pb.w) * sh;
        x2 = (pb.x + 0.5f * pb.z) * sw;
        y2 = (pb.y + 0.5f * pb.w) * sh;
        ar = fmaxf(x2 - x1, 0.f) * fmaxf(y2 - y1, 0.f);
    }
    sx1[tid] = x1; sy1[tid] = y1; sx2[tid] = x2; sy2[tid] = y2; sar[tid] = ar;
    __syncthreads();

    // ---- matrix slice (verified R5-R9; 16 slices, stride 256) ----
    unsigned* mat = wmat + (long)b * MATW;
    const int NG = (M + 3) >> 2;
    const int W64 = (M + 63) >> 6;
    for (int gi = slice * 16 + wave; gi < NG; gi += 256) {
        const int g = gi << 2;
        const int nr = min(4, M - g);
        const int wb = g >> 6;
        const int rl = 32 - 2 * wb;
        float ax1[4], ay1[4], ax2[4], ay2[4], aar[4];
        int rbase[4];
#pragma unroll
        for (int r = 0; r < 4; ++r) {
            int i = g + min(r, nr - 1);
            ax1[r] = sx1[i]; ay1[r] = sy1[i];
            ax2[r] = sx2[i]; ay2[r] = sy2[i]; aar[r] = sar[i];
            rbase[r] = rb32(wb) + ((g + r) & 63) * rl;
        }
        for (int w = wb; w < W64; ++w) {
            int j = (w << 6) | lane;
            float bx1 = sx1[j], by1 = sy1[j], bx2 = sx2[j], by2 = sy2[j], bar = sar[j];
#pragma unroll
            for (int r = 0; r < 4; ++r) {
                float ltx = fmaxf(ax1[r], bx1), lty = fmaxf(ay1[r], by1);
                float rbx = fminf(ax2[r], bx2), rby = fminf(ay2[r], by2);
                float wx = fmaxf(rbx - ltx, 0.f), wy = fmaxf(rby - lty, 0.f);
                float inter = wx * wy;
                float uni = aar[r] + bar - inter;       // exact ref op order
                float iou = inter / fmaxf(uni, 1e-9f);  // exact IEEE div
                bool sup = (iou > 0.5f) && (j > g + r);
                unsigned long long bal = __ballot(sup);
                if (lane == 0 && r < nr)
                    *(unsigned long long*)(mat + rbase[r] + 2 * (w - wb)) = bal;
            }
        }
    }
    // plain stores; visibility downstream guaranteed at kernel boundary
}

// ========== kernel 2: LDS-staged scan + scatter + epilogue ==========
__global__ __launch_bounds__(1024) void kfinal(
    const float* __restrict__ logits, const float* __restrict__ pboxes,
    const int* __restrict__ img_h_p, const int* __restrict__ img_w_p,
    const unsigned* __restrict__ wsM, const unsigned short* __restrict__ wsidx,
    const unsigned* __restrict__ wmat, float* __restrict__ out, int B)
{
    // smat u32[MATW]@0 (69632 B) | sidxl u16[NS]@69632 | keepq u8[QN]@71680
    // | skm u32[32]@73728.  fallback overlays @0: skeyF u64[QN] (16KB) |
    // ssupp u8[QN]@16384 (keepq/sidxl/skm untouched by overlay).
    __shared__ __align__(16) char smem[73856];
    unsigned* smat = (unsigned*)smem;
    unsigned short* sidxl = (unsigned short*)(smem + 69632);
    unsigned char* keepq = (unsigned char*)(smem + 71680);
    unsigned* skm = (unsigned*)(smem + 73728);

    const int b = blockIdx.x;
    const int tid = threadIdx.x;
    const float sw = (float)(*img_w_p), sh = (float)(*img_h_p);
    const int M = (int)wsM[b];

    // hoisted epilogue inputs (registers; latency hides under copy+scan)
    float2 l0 = ((const float2*)logits)[b * QN + tid];
    float2 l1 = ((const float2*)logits)[b * QN + tid + 1024];
    float4 p0 = ((const float4*)pboxes)[b * QN + tid];
    float4 p1 = ((const float4*)pboxes)[b * QN + tid + 1024];

    keepq[tid] = 0; keepq[tid + 1024] = 0;
    if (tid < 32) skm[tid] = 0;

    if (M <= NS) {
        // ---- stage matrix (vec4 coalesced) + sidxl into LDS (verified R9) ----
        const int W64 = (M + 63) >> 6;
        const int nw4 = rb32(W64) >> 2;          // rb32 is divisible by 4
        const uint4* gm4 = (const uint4*)(wmat + (long)b * MATW);
        uint4* sm4 = (uint4*)smat;
        for (int i = tid; i < nw4; i += 1024) sm4[i] = gm4[i];
        sidxl[tid] = wsidx[b * NS + tid];
        __syncthreads();

        // ---- single-wave BRANCHLESS ff1-free greedy scan (R10 core) ----
        if (tid < 64) {
            const unsigned* gm = smat;
            unsigned rem = 0;
            const int Ms = __builtin_amdgcn_readfirstlane(M);
            const int C = (Ms + 31) >> 5;
            const int lam = min(tid, 31);
            unsigned rcur[32];
            for (int c = 0; c < C; ++c) {
                // per-chunk addressing = verified R9 rnxt formula with cn := c
                const int wb = c >> 1, rl = 32 - 2 * wb;
                const int half = (c & 1) << 5;
                const int Lc = min(max(tid, 2 * wb), 31);
                const int rb0 = rb32(wb) + half * rl + (Lc - 2 * wb);
#pragma unroll
                for (int t = 0; t < 32; ++t) rcur[t] = gm[rb0 + t * rl];
                // diag lane t := row (32c+t)'s word (c-2wb) -- verified formula
                unsigned diag = gm[rb32(wb) + (half + lam) * rl + (c - 2 * wb)];

                int lim = min(32, Ms - (c << 5));
                unsigned limmask = (lim >= 32) ? 0xFFFFFFFFu : ((1u << lim) - 1u);
                // rw: suppressed-so-far word c; pre-suppress t >= lim
                unsigned rw = ((unsigned)__builtin_amdgcn_readlane((int)rem, c))
                              | ~limmask;
                unsigned keepmask = 0;
                // branchless ascending-t pops (rword bits <= t are 0 by j>i,
                // so order-exact vs the verified while/ctz loop)
#pragma unroll
                for (int t = 0; t < 32; ++t) {
                    unsigned keep = ((~rw) >> t) & 1u;
                    unsigned rword = (unsigned)__builtin_amdgcn_readlane((int)diag, t);
                    rw |= (0u - keep) & rword;
                    keepmask |= keep << t;
                }
                // merge kept rows into rem (branchless; final rem by OR-comm.)
#pragma unroll
                for (int t = 0; t < 32; ++t)
                    rem |= (0u - ((keepmask >> t) & 1u)) & rcur[t];
                if (tid == 0) skm[c] = keepmask;
            }
        }
        __syncthreads();
        // ---- scatter (verified R6) ----
        for (int s = tid; s < M; s += 1024)
            if ((skm[s >> 5] >> (s & 31)) & 1u) keepq[sidxl[s]] = 1;
        __syncthreads();
    } else {
        // ---- Fallback (M > NS, ~never): self-contained LDS sort + greedy ----
        unsigned long long* skeyF = (unsigned long long*)smem;
        unsigned char* ssupp = (unsigned char*)(smem + 16384);
        __syncthreads();   // keepq zeroing visible before use below
        for (int qq = tid; qq < QN; qq += 1024) {
            float2 l = ((const float2*)logits)[b * QN + qq];
            bool valid;
            skeyF[qq] = score_key(l, qq, &valid);
        }
        __syncthreads();
        for (int k = 2; k <= QN; k <<= 1)
            for (int j = k >> 1; j > 0; j >>= 1) {
                int i = ((tid & ~(j - 1)) << 1) | (tid & (j - 1));
                int p = i | j;
                bool up = ((i & k) == 0);
                unsigned long long a = skeyF[i], c2 = skeyF[p];
                if ((a > c2) == up) { skeyF[i] = c2; skeyF[p] = a; }
                __syncthreads();
            }
        for (int s = tid; s < M; s += 1024) ssupp[s] = 0;
        __syncthreads();
        for (int i = 0; i < M; ++i) {
            __syncthreads();
            if (ssupp[i]) continue;
            int ia = (unsigned short)(unsigned)skeyF[i];
            float4 pa = ((const float4*)pboxes)[b * QN + ia];
            float ax1 = (pa.x - 0.5f * pa.z) * sw, ay1 = (pa.y - 0.5f * pa.w) * sh;
            float ax2 = (pa.x + 0.5f * pa.z) * sw, ay2 = (pa.y + 0.5f * pa.w) * sh;
            float areaA = fmaxf(ax2 - ax1, 0.f) * fmaxf(ay2 - ay1, 0.f);
            for (int jj = i + 1 + tid; jj < M; jj += 1024) {
                int jb = (unsigned short)(unsigned)skeyF[jj];
                float4 pq = ((const float4*)pboxes)[b * QN + jb];
                float bx1 = (pq.x - 0.5f * pq.z) * sw, by1 = (pq.y - 0.5f * pq.w) * sh;
                float bx2 = (pq.x + 0.5f * pq.z) * sw, by2 = (pq.y + 0.5f * pq.w) * sh;
                float ltx = fmaxf(ax1, bx1), lty = fmaxf(ay1, by1);
                float rbx = fminf(ax2, bx2), rby = fminf(ay2, by2);
                float wx = fmaxf(rbx - ltx, 0.f), wy = fmaxf(rby - lty, 0.f);
                float inter = wx * wy;
                float areaB = fmaxf(bx2 - bx1, 0.f) * fmaxf(by2 - by1, 0.f);
                float uni = areaA + areaB - inter;
                if (inter / fmaxf(uni, 1e-9f) > 0.5f) ssupp[jj] = 1;
            }
        }
        __syncthreads();
        for (int s = tid; s < M; s += 1024)
            if (!ssupp[s]) keepq[(unsigned short)(unsigned)skeyF[s]] = 1;
        __syncthreads();
    }

    // ---- epilogue from hoisted registers (formulas verbatim R6/R9) ----
    const long BQ = (long)B * QN;
    {
        int base = b * QN + tid;
        float e = expf(fminf(l0.x, l0.y) - fmaxf(l0.x, l0.y));
        float score = 1.0f / (1.0f + e);
        float x1 = (p0.x - 0.5f * p0.z) * sw, y1 = (p0.y - 0.5f * p0.w) * sh;
        float x2 = (p0.x + 0.5f * p0.z) * sw, y2 = (p0.y + 0.5f * p0.w) * sh;
        int kp = keepq[tid];
        out[base] = kp ? score : 0.f;
        out[BQ * 5 + base] = kp ? 1.f : 0.f;
        float4 ob;
        ob.x = kp ? truncf(x1) : 0.f;
        ob.y = kp ? truncf(y1) : 0.f;
        ob.z = kp ? truncf(x2) : 0.f;
        ob.w = kp ? truncf(y2) : 0.f;
        ((float4*)(out + BQ))[base] = ob;
    }
    {
        int base = b * QN + tid + 1024;
        float e = expf(fminf(l1.x, l1.y) - fmaxf(l1.x, l1.y));
        float score = 1.0f / (1.0f + e);
        float x1 = (p1.x - 0.5f * p1.z) * sw, y1 = (p1.y - 0.5f * p1.w) * sh;
        float x2 = (p1.x + 0.5f * p1.z) * sw, y2 = (p1.y + 0.5f * p1.w) * sh;
        int kp = keepq[tid + 1024];
        out[base] = kp ? score : 0.f;
        out[BQ * 5 + base] = kp ? 1.f : 0.f;
        float4 ob;
        ob.x = kp ? truncf(x1) : 0.f;
        ob.y = kp ? truncf(y1) : 0.f;
        ob.z = kp ? truncf(x2) : 0.f;
        ob.w = kp ? truncf(y2) : 0.f;
        ((float4*)(out + BQ))[base] = ob;
    }
}

extern "C" void kernel_launch(void* const* d_in, const int* in_sizes, int n_in,
                              void* d_out, int out_size, void* d_ws, size_t ws_size,
                              hipStream_t stream) {
    const float* logits = (const float*)d_in[0];
    const float* pboxes = (const float*)d_in[1];
    const int*   img_h  = (const int*)d_in[2];
    const int*   img_w  = (const int*)d_in[3];
    float* out = (float*)d_out;
    const int B = in_sizes[0] / (QN * 2);   // 16

    char* ws = (char*)d_ws;                 // footprint 1,147,904 B (= proven R6-R9)
    unsigned*       wsM   = (unsigned*)(ws + 0);
    unsigned short* wsidx = (unsigned short*)(ws + WSIDX);
    unsigned*       wmat  = (unsigned*)(ws + WSMAT);

    kprep<<<dim3(B * NSLICE), dim3(1024), 0, stream>>>(logits, pboxes, img_h, img_w,
                                                       wsM, wsidx, wmat, B);
    kfinal<<<dim3(B), dim3(1024), 0, stream>>>(logits, pboxes, img_h, img_w,
                                               wsM, wsidx, wmat, out, B);
}

// Round 11
// 97.135 us; speedup vs baseline: 1.2991x; 1.0082x over previous
//
#include <hip/hip_runtime.h>
#include <math.h>

// PostProcess: B=16, Q=2048, C=2. R11: back to ONE kernel (grid B*16 x 1024),
// assembling only verified pieces + an inverted epilogue:
//  - producer skeleton, 16 slices, MAGIC flags: verbatim R5 (passed, 6 rounds)
//  - consumer: LDS-staged branchless scan: verbatim R10 (passed)
//  - epilogue INVERTED: each producer slice zero-writes its 128-q output
//    stripe BEFORE its release flag (zeros are the exact output for every
//    non-kept q); the consumer, after the acquire-spin (orders those stores),
//    scatter-writes only the ~120 KEPT entries. Deletes: one launch boundary,
//    the all-images global barrier between kernels (consumer of image b starts
//    when ITS slices finish), kfinal's 1.5MB hoisted loads + full store pass.
// LDS: producer region 0..41216 | smat @41216 (69632B) -> 110848 total
//      (1 block/CU; grid = 256 = CU count). skm reuses dead skeyB @33024.
// ws: flags u32[256]@0 | mat u32[16][17408]@1024  (1,115,136 B < proven 1.148MB)

#define QN     2048
#define NS     1024      // fast-path max valid boxes (E[M]=562, sd~20; M>NS ~23 sigma)
#define NSLICE 16
#define MATW   17408     // ragged u32 words/image = 64 * sum_{wb<16}(32-2wb)
#define MAGIC  0x5ca1ab1eu

__device__ __forceinline__ int rb32(int wb) { return 64 * wb * (33 - wb); }

__device__ __forceinline__ unsigned long long shfl_xor_u64(unsigned long long x, int m) {
    int lo = __shfl_xor((int)(unsigned)(x & 0xffffffffull), m, 64);
    int hi = __shfl_xor((int)(unsigned)(x >> 32), m, 64);
    return ((unsigned long long)(unsigned)hi << 32) | (unsigned)lo;
}

// ascending key order == score desc, idx asc (stable); invalid -> tail.
__device__ __forceinline__ unsigned long long score_key(float2 l, int q, bool* valid_out) {
    float mx = fmaxf(l.x, l.y), mn = fminf(l.x, l.y);
    float e = expf(mn - mx);
    float score = 1.0f / (1.0f + e);                 // max softmax prob (exact ref order)
    bool valid = (l.x >= l.y) && (score >= 0.7f);    // argmax tie -> class 0
    *valid_out = valid;
    unsigned sbits = valid ? __float_as_uint(score) : 0u;
    return ((unsigned long long)(~sbits) << 32) | (unsigned)q;
}

__global__ __launch_bounds__(1024) void kfused(
    const float* __restrict__ logits, const float* __restrict__ pboxes,
    const int* __restrict__ img_h_p, const int* __restrict__ img_w_p,
    unsigned* __restrict__ wflag, unsigned* __restrict__ wmat,
    float* __restrict__ out, int B)
{
    // producer: skey u64[NS]@0 | sx1@8192 sy1@12288 sx2@16384 sy2@20480
    //           sar@24576 | sidxl u16[NS]@28672 | sM@32896 | skeyB u64[NS]@33024
    // consumer: skm u32[32]@33024 (skeyB dead after sort) | smat u32[MATW]@41216
    // fallback overlays @0: skeyF u64[QN] (16KB) | ssupp@16384 | keepqF@18432
    __shared__ __align__(16) char smem[110848];
    unsigned long long* skey = (unsigned long long*)smem;
    float* sx1 = (float*)(smem + 8192);
    float* sy1 = (float*)(smem + 12288);
    float* sx2 = (float*)(smem + 16384);
    float* sy2 = (float*)(smem + 20480);
    float* sar = (float*)(smem + 24576);
    unsigned short* sidxl = (unsigned short*)(smem + 28672);
    int* sMp = (int*)(smem + 32896);
    unsigned long long* skeyB = (unsigned long long*)(smem + 33024);
    unsigned* skm = (unsigned*)(smem + 33024);
    unsigned* smat = (unsigned*)(smem + 41216);

    const int blk = blockIdx.x;
    const int b = blk % B, slice = blk / B;
    const int tid = threadIdx.x, lane = tid & 63, wave = tid >> 6;
    const float sw = (float)(*img_w_p), sh = (float)(*img_h_p);
    const long BQ = (long)B * QN;

    if (tid == 0) *sMp = 0;
    __syncthreads();

    // ---- compact valid keys (ballot compaction; verified R4-R10) ----
    const unsigned long long lmask_lt = (1ull << lane) - 1ull;
#pragma unroll
    for (int qq = 0; qq < 2; ++qq) {
        int q = tid + qq * 1024;
        float2 l = ((const float2*)logits)[b * QN + q];
        bool valid;
        unsigned long long key = score_key(l, q, &valid);
        unsigned long long mb = __ballot(valid);
        int base = 0;
        if (lane == 0 && mb) base = atomicAdd(sMp, __popcll(mb));
        base = __shfl(base, 0, 64);
        if (valid) {
            int slot = base + __popcll(mb & lmask_lt);
            if (slot < NS) skey[slot] = key;
        }
    }
    __syncthreads();
    const int M = *sMp;

    if (M <= NS) {
        // ---- register bitonic sort of NS u64, 1 elem/thread (verified R4/R5) ----
        unsigned long long v = (tid < M) ? skey[tid] : ~0ull;
        __syncthreads();   // skey reused as exchange buffer
#pragma unroll
        for (int k = 2; k <= 64; k <<= 1) {
            bool dir = ((tid & k) == 0);
#pragma unroll
            for (int j = k >> 1; j > 0; j >>= 1) {
                unsigned long long o = shfl_xor_u64(v, j);
                bool takeMin = (dir == ((tid & j) == 0));
                v = ((v < o) == takeMin) ? v : o;
            }
        }
        int pp = 0;
        for (int k = 128; k <= NS; k <<= 1) {
            bool dir = ((tid & k) == 0);
            for (int j = k >> 1; j >= 64; j >>= 1) {
                unsigned long long* buf = pp ? skeyB : skey;
                pp ^= 1;
                buf[tid] = v;
                __syncthreads();
                unsigned long long o = buf[tid ^ j];
                bool takeMin = (dir == ((tid & j) == 0));
                v = ((v < o) == takeMin) ? v : o;
            }
#pragma unroll
            for (int j = 32; j > 0; j >>= 1) {
                unsigned long long o = shfl_xor_u64(v, j);
                bool takeMin = (dir == ((tid & j) == 0));
                v = ((v < o) == takeMin) ? v : o;
            }
        }
        // sorted SoA (padding slots zero -> iou 0)
        int qi = (int)((unsigned)v & 0xffffu);
        sidxl[tid] = (unsigned short)qi;
        float x1 = 0.f, y1 = 0.f, x2 = 0.f, y2 = 0.f, ar = 0.f;
        if (tid < M) {
            float4 pb = ((const float4*)pboxes)[b * QN + qi];
            x1 = (pb.x - 0.5f * pb.z) * sw;
            y1 = (pb.y - 0.5f * pb.w) * sh;
            x2 = (pb.x + 0.5f * pb.z) * sw;
            y2 = (pb.y + 0.5f * pb.w) * sh;
            ar = fmaxf(x2 - x1, 0.f) * fmaxf(y2 - y1, 0.f);
        }
        sx1[tid] = x1; sy1[tid] = y1; sx2[tid] = x2; sy2[tid] = y2; sar[tid] = ar;
        __syncthreads();

        // ---- matrix slice (verified R5-R10; 16 slices, stride 256) ----
        unsigned* mat = wmat + (long)b * MATW;
        const int NG = (M + 3) >> 2;
        const int W64 = (M + 63) >> 6;
        for (int gi = slice * 16 + wave; gi < NG; gi += 256) {
            const int g = gi << 2;
            const int nr = min(4, M - g);
            const int wb = g >> 6;
            const int rl = 32 - 2 * wb;
            float ax1[4], ay1[4], ax2[4], ay2[4], aar[4];
            int rbase[4];
#pragma unroll
            for (int r = 0; r < 4; ++r) {
                int i = g + min(r, nr - 1);
                ax1[r] = sx1[i]; ay1[r] = sy1[i];
                ax2[r] = sx2[i]; ay2[r] = sy2[i]; aar[r] = sar[i];
                rbase[r] = rb32(wb) + ((g + r) & 63) * rl;
            }
            for (int w = wb; w < W64; ++w) {
                int j = (w << 6) | lane;
                float bx1 = sx1[j], by1 = sy1[j], bx2 = sx2[j], by2 = sy2[j], bar = sar[j];
#pragma unroll
                for (int r = 0; r < 4; ++r) {
                    float ltx = fmaxf(ax1[r], bx1), lty = fmaxf(ay1[r], by1);
                    float rbx = fminf(ax2[r], bx2), rby = fminf(ay2[r], by2);
                    float wx = fmaxf(rbx - ltx, 0.f), wy = fmaxf(rby - lty, 0.f);
                    float inter = wx * wy;
                    float uni = aar[r] + bar - inter;       // exact ref op order
                    float iou = inter / fmaxf(uni, 1e-9f);  // exact IEEE div
                    bool sup = (iou > 0.5f) && (j > g + r);
                    unsigned long long bal = __ballot(sup);
                    if (lane == 0 && r < nr)
                        *(unsigned long long*)(mat + rbase[r] + 2 * (w - wb)) = bal;
                }
            }
        }
    }

    // ---- inverted epilogue part 1: zero-write this slice's 128-q stripe ----
    // zeros are the exact outputs for every non-kept q (score=0,label=0,box=0);
    // consumer overwrites kept entries after the acquire-spin orders these.
    if (tid < 128) {
        int q = slice * 128 + tid;
        int base = b * QN + q;
        out[base] = 0.f;
        out[BQ * 5 + base] = 0.f;
        float4 z; z.x = 0.f; z.y = 0.f; z.z = 0.f; z.w = 0.f;
        ((float4*)(out + BQ))[base] = z;
    }

    __syncthreads();   // drains matrix + zero stores (vmcnt 0 at barrier)
    if (tid == 0)
        __hip_atomic_store(&wflag[b * NSLICE + slice], MAGIC,
                           __ATOMIC_RELEASE, __HIP_MEMORY_SCOPE_AGENT);
    if (slice != 0) return;    // producers done; consumer block continues

    // ---- consumer: spin for all 16 slices (verified R5 MAGIC scheme) ----
    if (wave == 0) {
        const unsigned* fp = &wflag[b * NSLICE + (lane & (NSLICE - 1))];
        for (;;) {
            unsigned f = (lane < NSLICE)
                ? __hip_atomic_load(fp, __ATOMIC_ACQUIRE, __HIP_MEMORY_SCOPE_AGENT)
                : MAGIC;
            if (__all(f == MAGIC)) break;
            __builtin_amdgcn_s_sleep(2);
        }
    }
    __syncthreads();   // all 16 waves held until flags acquired

    if (M <= NS) {
        // ---- stage matrix (vec4 coalesced) into LDS (verified R9/R10) ----
        const int W64 = (M + 63) >> 6;
        const int nw4 = rb32(W64) >> 2;          // rb32 is divisible by 4
        const uint4* gm4 = (const uint4*)(wmat + (long)b * MATW);
        uint4* sm4 = (uint4*)smat;
        for (int i = tid; i < nw4; i += 1024) sm4[i] = gm4[i];
        __syncthreads();

        // ---- single-wave branchless greedy scan (verbatim R10 core) ----
        if (tid < 64) {
            const unsigned* gm = smat;
            unsigned rem = 0;
            const int Ms = __builtin_amdgcn_readfirstlane(M);
            const int C = (Ms + 31) >> 5;
            const int lam = min(tid, 31);
            unsigned rcur[32];
            for (int c = 0; c < C; ++c) {
                const int wb = c >> 1, rl = 32 - 2 * wb;
                const int half = (c & 1) << 5;
                const int Lc = min(max(tid, 2 * wb), 31);
                const int rb0 = rb32(wb) + half * rl + (Lc - 2 * wb);
#pragma unroll
                for (int t = 0; t < 32; ++t) rcur[t] = gm[rb0 + t * rl];
                unsigned diag = gm[rb32(wb) + (half + lam) * rl + (c - 2 * wb)];

                int lim = min(32, Ms - (c << 5));
                unsigned limmask = (lim >= 32) ? 0xFFFFFFFFu : ((1u << lim) - 1u);
                unsigned rw = ((unsigned)__builtin_amdgcn_readlane((int)rem, c))
                              | ~limmask;
                unsigned keepmask = 0;
#pragma unroll
                for (int t = 0; t < 32; ++t) {
                    unsigned keep = ((~rw) >> t) & 1u;
                    unsigned rword = (unsigned)__builtin_amdgcn_readlane((int)diag, t);
                    rw |= (0u - keep) & rword;
                    keepmask |= keep << t;
                }
#pragma unroll
                for (int t = 0; t < 32; ++t)
                    rem |= (0u - ((keepmask >> t) & 1u)) & rcur[t];
                if (tid == 0) skm[c] = keepmask;
            }
        }
        __syncthreads();

        // ---- inverted epilogue part 2: write ONLY kept entries ----
        for (int s = tid; s < M; s += 1024) {
            if ((skm[s >> 5] >> (s & 31)) & 1u) {
                int qi = sidxl[s];
                int base = b * QN + qi;
                float2 l = ((const float2*)logits)[base];
                float e = expf(fminf(l.x, l.y) - fmaxf(l.x, l.y));
                float score = 1.0f / (1.0f + e);
                float4 pb = ((const float4*)pboxes)[base];
                float x1 = (pb.x - 0.5f * pb.z) * sw, y1 = (pb.y - 0.5f * pb.w) * sh;
                float x2 = (pb.x + 0.5f * pb.z) * sw, y2 = (pb.y + 0.5f * pb.w) * sh;
                out[base] = score;
                out[BQ * 5 + base] = 1.f;
                float4 ob;
                ob.x = truncf(x1); ob.y = truncf(y1);
                ob.z = truncf(x2); ob.w = truncf(y2);
                ((float4*)(out + BQ))[base] = ob;
            }
        }
    } else {
        // ---- Fallback (M > NS, ~never): self-contained sort + greedy + full
        //      epilogue (overwrites producers' zeros; ordered by acquire) ----
        unsigned long long* skeyF = (unsigned long long*)smem;
        unsigned char* ssupp = (unsigned char*)(smem + 16384);
        unsigned char* keepqF = (unsigned char*)(smem + 18432);
        for (int qq = tid; qq < QN; qq += 1024) {
            float2 l = ((const float2*)logits)[b * QN + qq];
            bool valid;
            skeyF[qq] = score_key(l, qq, &valid);
        }
        keepqF[tid] = 0; keepqF[tid + 1024] = 0;
        __syncthreads();
        for (int k = 2; k <= QN; k <<= 1)
            for (int j = k >> 1; j > 0; j >>= 1) {
                int i = ((tid & ~(j - 1)) << 1) | (tid & (j - 1));
                int p = i | j;
                bool up = ((i & k) == 0);
                unsigned long long a = skeyF[i], c2 = skeyF[p];
                if ((a > c2) == up) { skeyF[i] = c2; skeyF[p] = a; }
                __syncthreads();
            }
        for (int s = tid; s < M; s += 1024) ssupp[s] = 0;
        __syncthreads();
        for (int i = 0; i < M; ++i) {
            __syncthreads();
            if (ssupp[i]) continue;
            int ia = (unsigned short)(unsigned)skeyF[i];
            float4 pa = ((const float4*)pboxes)[b * QN + ia];
            float ax1 = (pa.x - 0.5f * pa.z) * sw, ay1 = (pa.y - 0.5f * pa.w) * sh;
            float ax2 = (pa.x + 0.5f * pa.z) * sw, ay2 = (pa.y + 0.5f * pa.w) * sh;
            float areaA = fmaxf(ax2 - ax1, 0.f) * fmaxf(ay2 - ay1, 0.f);
            for (int jj = i + 1 + tid; jj < M; jj += 1024) {
                int jb = (unsigned short)(unsigned)skeyF[jj];
                float4 pq = ((const float4*)pboxes)[b * QN + jb];
                float bx1 = (pq.x - 0.5f * pq.z) * sw, by1 = (pq.y - 0.5f * pq.w) * sh;
                float bx2 = (pq.x + 0.5f * pq.z) * sw, by2 = (pq.y + 0.5f * pq.w) * sh;
                float ltx = fmaxf(ax1, bx1), lty = fmaxf(ay1, by1);
                float rbx = fminf(ax2, bx2), rby = fminf(ay2, by2);
                float wx = fmaxf(rbx - ltx, 0.f), wy = fmaxf(rby - lty, 0.f);
                float inter = wx * wy;
                float areaB = fmaxf(bx2 - bx1, 0.f) * fmaxf(by2 - by1, 0.f);
                float uni = areaA + areaB - inter;
                if (inter / fmaxf(uni, 1e-9f) > 0.5f) ssupp[jj] = 1;
            }
        }
        __syncthreads();
        for (int s = tid; s < M; s += 1024)
            if (!ssupp[s]) keepqF[(unsigned short)(unsigned)skeyF[s]] = 1;
        __syncthreads();
#pragma unroll
        for (int qq = 0; qq < 2; ++qq) {
            int q = tid + qq * 1024;
            int base = b * QN + q;
            float2 l = ((const float2*)logits)[base];
            float e = expf(fminf(l.x, l.y) - fmaxf(l.x, l.y));
            float score = 1.0f / (1.0f + e);
            float4 pb = ((const float4*)pboxes)[base];
            float x1 = (pb.x - 0.5f * pb.z) * sw, y1 = (pb.y - 0.5f * pb.w) * sh;
            float x2 = (pb.x + 0.5f * pb.z) * sw, y2 = (pb.y + 0.5f * pb.w) * sh;
            int kp = keepqF[q];
            out[base] = kp ? score : 0.f;
            out[BQ * 5 + base] = kp ? 1.f : 0.f;
            float4 ob;
            ob.x = kp ? truncf(x1) : 0.f;
            ob.y = kp ? truncf(y1) : 0.f;
            ob.z = kp ? truncf(x2) : 0.f;
            ob.w = kp ? truncf(y2) : 0.f;
            ((float4*)(out + BQ))[base] = ob;
        }
    }
}

extern "C" void kernel_launch(void* const* d_in, const int* in_sizes, int n_in,
                              void* d_out, int out_size, void* d_ws, size_t ws_size,
                              hipStream_t stream) {
    const float* logits = (const float*)d_in[0];
    const float* pboxes = (const float*)d_in[1];
    const int*   img_h  = (const int*)d_in[2];
    const int*   img_w  = (const int*)d_in[3];
    float* out = (float*)d_out;
    const int B = in_sizes[0] / (QN * 2);   // 16

    char* ws = (char*)d_ws;                 // footprint 1,115,136 B (< proven 1.148MB)
    unsigned* wflag = (unsigned*)(ws + 0);
    unsigned* wmat  = (unsigned*)(ws + 1024);

    kfused<<<dim3(B * NSLICE), dim3(1024), 0, stream>>>(logits, pboxes, img_h, img_w,
                                                        wflag, wmat, out, B);
}

// Round 12
// 95.138 us; speedup vs baseline: 1.3264x; 1.0210x over previous
//
#include <hip/hip_runtime.h>
#include <math.h>

// PostProcess: B=16, Q=2048, C=2. R12 = R11 (97.1us, passing) + ONE isolated
// change: the consumer scan's rcur-load + merge phases are SPLIT ACROSS BOTH
// WAVE HALVES. R11 evidence chain (R9 -2.9, R10 -0.9, R11 -0.8) back-solves to
// scan ~650cy/chunk x 18 at ~0.6-1GHz idle-tail clock ~= 15us; loads (200cy)
// and merge (192cy) ran on lanes 0-31 only, lanes 32-63 duplicating lane 31.
// Now: lanes 0-31 handle rows t in [0,16), lanes 32-63 rows [16,32) (same
// verified address formulas; word-slot Lc from tid&31), one shfl_xor(32)
// recombines partial ORs. Pop chain / diag / limmask / skm verbatim R11.
// ws: flags u32[256]@0 | mat u32[16][17408]@1024  (1,115,136 B < proven 1.148MB)

#define QN     2048
#define NS     1024      // fast-path max valid boxes (E[M]=562, sd~20; M>NS ~23 sigma)
#define NSLICE 16
#define MATW   17408     // ragged u32 words/image = 64 * sum_{wb<16}(32-2wb)
#define MAGIC  0x5ca1ab1eu

__device__ __forceinline__ int rb32(int wb) { return 64 * wb * (33 - wb); }

__device__ __forceinline__ unsigned long long shfl_xor_u64(unsigned long long x, int m) {
    int lo = __shfl_xor((int)(unsigned)(x & 0xffffffffull), m, 64);
    int hi = __shfl_xor((int)(unsigned)(x >> 32), m, 64);
    return ((unsigned long long)(unsigned)hi << 32) | (unsigned)lo;
}

// ascending key order == score desc, idx asc (stable); invalid -> tail.
__device__ __forceinline__ unsigned long long score_key(float2 l, int q, bool* valid_out) {
    float mx = fmaxf(l.x, l.y), mn = fminf(l.x, l.y);
    float e = expf(mn - mx);
    float score = 1.0f / (1.0f + e);                 // max softmax prob (exact ref order)
    bool valid = (l.x >= l.y) && (score >= 0.7f);    // argmax tie -> class 0
    *valid_out = valid;
    unsigned sbits = valid ? __float_as_uint(score) : 0u;
    return ((unsigned long long)(~sbits) << 32) | (unsigned)q;
}

__global__ __launch_bounds__(1024) void kfused(
    const float* __restrict__ logits, const float* __restrict__ pboxes,
    const int* __restrict__ img_h_p, const int* __restrict__ img_w_p,
    unsigned* __restrict__ wflag, unsigned* __restrict__ wmat,
    float* __restrict__ out, int B)
{
    // producer: skey u64[NS]@0 | sx1@8192 sy1@12288 sx2@16384 sy2@20480
    //           sar@24576 | sidxl u16[NS]@28672 | sM@32896 | skeyB u64[NS]@33024
    // consumer: skm u32[32]@33024 (skeyB dead after sort) | smat u32[MATW]@41216
    // fallback overlays @0: skeyF u64[QN] (16KB) | ssupp@16384 | keepqF@18432
    __shared__ __align__(16) char smem[110848];
    unsigned long long* skey = (unsigned long long*)smem;
    float* sx1 = (float*)(smem + 8192);
    float* sy1 = (float*)(smem + 12288);
    float* sx2 = (float*)(smem + 16384);
    float* sy2 = (float*)(smem + 20480);
    float* sar = (float*)(smem + 24576);
    unsigned short* sidxl = (unsigned short*)(smem + 28672);
    int* sMp = (int*)(smem + 32896);
    unsigned long long* skeyB = (unsigned long long*)(smem + 33024);
    unsigned* skm = (unsigned*)(smem + 33024);
    unsigned* smat = (unsigned*)(smem + 41216);

    const int blk = blockIdx.x;
    const int b = blk % B, slice = blk / B;
    const int tid = threadIdx.x, lane = tid & 63, wave = tid >> 6;
    const float sw = (float)(*img_w_p), sh = (float)(*img_h_p);
    const long BQ = (long)B * QN;

    if (tid == 0) *sMp = 0;
    __syncthreads();

    // ---- compact valid keys (ballot compaction; verified R4-R11) ----
    const unsigned long long lmask_lt = (1ull << lane) - 1ull;
#pragma unroll
    for (int qq = 0; qq < 2; ++qq) {
        int q = tid + qq * 1024;
        float2 l = ((const float2*)logits)[b * QN + q];
        bool valid;
        unsigned long long key = score_key(l, q, &valid);
        unsigned long long mb = __ballot(valid);
        int base = 0;
        if (lane == 0 && mb) base = atomicAdd(sMp, __popcll(mb));
        base = __shfl(base, 0, 64);
        if (valid) {
            int slot = base + __popcll(mb & lmask_lt);
            if (slot < NS) skey[slot] = key;
        }
    }
    __syncthreads();
    const int M = *sMp;

    if (M <= NS) {
        // ---- register bitonic sort of NS u64, 1 elem/thread (verified R4/R5) ----
        unsigned long long v = (tid < M) ? skey[tid] : ~0ull;
        __syncthreads();   // skey reused as exchange buffer
#pragma unroll
        for (int k = 2; k <= 64; k <<= 1) {
            bool dir = ((tid & k) == 0);
#pragma unroll
            for (int j = k >> 1; j > 0; j >>= 1) {
                unsigned long long o = shfl_xor_u64(v, j);
                bool takeMin = (dir == ((tid & j) == 0));
                v = ((v < o) == takeMin) ? v : o;
            }
        }
        int pp = 0;
        for (int k = 128; k <= NS; k <<= 1) {
            bool dir = ((tid & k) == 0);
            for (int j = k >> 1; j >= 64; j >>= 1) {
                unsigned long long* buf = pp ? skeyB : skey;
                pp ^= 1;
                buf[tid] = v;
                __syncthreads();
                unsigned long long o = buf[tid ^ j];
                bool takeMin = (dir == ((tid & j) == 0));
                v = ((v < o) == takeMin) ? v : o;
            }
#pragma unroll
            for (int j = 32; j > 0; j >>= 1) {
                unsigned long long o = shfl_xor_u64(v, j);
                bool takeMin = (dir == ((tid & j) == 0));
                v = ((v < o) == takeMin) ? v : o;
            }
        }
        // sorted SoA (padding slots zero -> iou 0)
        int qi = (int)((unsigned)v & 0xffffu);
        sidxl[tid] = (unsigned short)qi;
        float x1 = 0.f, y1 = 0.f, x2 = 0.f, y2 = 0.f, ar = 0.f;
        if (tid < M) {
            float4 pb = ((const float4*)pboxes)[b * QN + qi];
            x1 = (pb.x - 0.5f * pb.z) * sw;
            y1 = (pb.y - 0.5f * pb.w) * sh;
            x2 = (pb.x + 0.5f * pb.z) * sw;
            y2 = (pb.y + 0.5f * pb.w) * sh;
            ar = fmaxf(x2 - x1, 0.f) * fmaxf(y2 - y1, 0.f);
        }
        sx1[tid] = x1; sy1[tid] = y1; sx2[tid] = x2; sy2[tid] = y2; sar[tid] = ar;
        __syncthreads();

        // ---- matrix slice (verified R5-R11; 16 slices, stride 256) ----
        unsigned* mat = wmat + (long)b * MATW;
        const int NG = (M + 3) >> 2;
        const int W64 = (M + 63) >> 6;
        for (int gi = slice * 16 + wave; gi < NG; gi += 256) {
            const int g = gi << 2;
            const int nr = min(4, M - g);
            const int wb = g >> 6;
            const int rl = 32 - 2 * wb;
            float ax1[4], ay1[4], ax2[4], ay2[4], aar[4];
            int rbase[4];
#pragma unroll
            for (int r = 0; r < 4; ++r) {
                int i = g + min(r, nr - 1);
                ax1[r] = sx1[i]; ay1[r] = sy1[i];
                ax2[r] = sx2[i]; ay2[r] = sy2[i]; aar[r] = sar[i];
                rbase[r] = rb32(wb) + ((g + r) & 63) * rl;
            }
            for (int w = wb; w < W64; ++w) {
                int j = (w << 6) | lane;
                float bx1 = sx1[j], by1 = sy1[j], bx2 = sx2[j], by2 = sy2[j], bar = sar[j];
#pragma unroll
                for (int r = 0; r < 4; ++r) {
                    float ltx = fmaxf(ax1[r], bx1), lty = fmaxf(ay1[r], by1);
                    float rbx = fminf(ax2[r], bx2), rby = fminf(ay2[r], by2);
                    float wx = fmaxf(rbx - ltx, 0.f), wy = fmaxf(rby - lty, 0.f);
                    float inter = wx * wy;
                    float uni = aar[r] + bar - inter;       // exact ref op order
                    float iou = inter / fmaxf(uni, 1e-9f);  // exact IEEE div
                    bool sup = (iou > 0.5f) && (j > g + r);
                    unsigned long long bal = __ballot(sup);
                    if (lane == 0 && r < nr)
                        *(unsigned long long*)(mat + rbase[r] + 2 * (w - wb)) = bal;
                }
            }
        }
    }

    // ---- inverted epilogue part 1: zero-write this slice's 128-q stripe ----
    if (tid < 128) {
        int q = slice * 128 + tid;
        int base = b * QN + q;
        out[base] = 0.f;
        out[BQ * 5 + base] = 0.f;
        float4 z; z.x = 0.f; z.y = 0.f; z.z = 0.f; z.w = 0.f;
        ((float4*)(out + BQ))[base] = z;
    }

    __syncthreads();   // drains matrix + zero stores (vmcnt 0 at barrier)
    if (tid == 0)
        __hip_atomic_store(&wflag[b * NSLICE + slice], MAGIC,
                           __ATOMIC_RELEASE, __HIP_MEMORY_SCOPE_AGENT);
    if (slice != 0) return;    // producers done; consumer block continues

    // ---- consumer: spin for all 16 slices (verified R5/R11 MAGIC scheme) ----
    if (wave == 0) {
        const unsigned* fp = &wflag[b * NSLICE + (lane & (NSLICE - 1))];
        for (;;) {
            unsigned f = (lane < NSLICE)
                ? __hip_atomic_load(fp, __ATOMIC_ACQUIRE, __HIP_MEMORY_SCOPE_AGENT)
                : MAGIC;
            if (__all(f == MAGIC)) break;
            __builtin_amdgcn_s_sleep(2);
        }
    }
    __syncthreads();   // all 16 waves held until flags acquired

    if (M <= NS) {
        // ---- stage matrix (vec4 coalesced) into LDS (verified R9-R11) ----
        const int W64 = (M + 63) >> 6;
        const int nw4 = rb32(W64) >> 2;          // rb32 is divisible by 4
        const uint4* gm4 = (const uint4*)(wmat + (long)b * MATW);
        uint4* sm4 = (uint4*)smat;
        for (int i = tid; i < nw4; i += 1024) sm4[i] = gm4[i];
        __syncthreads();

        // ---- single-wave scan, loads+merge split across wave halves ----
        if (tid < 64) {
            const unsigned* gm = smat;
            unsigned rem = 0;
            const int Ms = __builtin_amdgcn_readfirstlane(M);
            const int C = (Ms + 31) >> 5;
            const int lam = min(tid, 31);
            const int tb = (tid >> 5) << 4;      // rows [0,16) / [16,32) per half
            unsigned r16[16];
            for (int c = 0; c < C; ++c) {
                const int wb = c >> 1, rl = 32 - 2 * wb;
                const int half = (c & 1) << 5;
                const int Lc = min(max((int)(tid & 31), 2 * wb), 31);
                const int rb0 = rb32(wb) + half * rl + (Lc - 2 * wb);
                // half-split loads: 16 rows per lane-half (same verified formula)
#pragma unroll
                for (int t = 0; t < 16; ++t) r16[t] = gm[rb0 + (tb + t) * rl];
                // diag lane t := row (32c+t)'s word (c-2wb) -- verbatim R10/R11
                unsigned diag = gm[rb32(wb) + (half + lam) * rl + (c - 2 * wb)];

                int lim = min(32, Ms - (c << 5));
                unsigned limmask = (lim >= 32) ? 0xFFFFFFFFu : ((1u << lim) - 1u);
                unsigned rw = ((unsigned)__builtin_amdgcn_readlane((int)rem, c))
                              | ~limmask;
                unsigned keepmask = 0;
                // branchless pop chain (verbatim R10/R11)
#pragma unroll
                for (int t = 0; t < 32; ++t) {
                    unsigned keep = ((~rw) >> t) & 1u;
                    unsigned rword = (unsigned)__builtin_amdgcn_readlane((int)diag, t);
                    rw |= (0u - keep) & rword;
                    keepmask |= keep << t;
                }
                // half-split merge + cross-half recombine
                unsigned part = 0;
#pragma unroll
                for (int t = 0; t < 16; ++t)
                    part |= (0u - ((keepmask >> (tb + t)) & 1u)) & r16[t];
                part |= (unsigned)__shfl_xor((int)part, 32, 64);
                rem |= part;
                if (tid == 0) skm[c] = keepmask;
            }
        }
        __syncthreads();

        // ---- inverted epilogue part 2: write ONLY kept entries (verified R11) ----
        for (int s = tid; s < M; s += 1024) {
            if ((skm[s >> 5] >> (s & 31)) & 1u) {
                int qi = sidxl[s];
                int base = b * QN + qi;
                float2 l = ((const float2*)logits)[base];
                float e = expf(fminf(l.x, l.y) - fmaxf(l.x, l.y));
                float score = 1.0f / (1.0f + e);
                float4 pb = ((const float4*)pboxes)[base];
                float x1 = (pb.x - 0.5f * pb.z) * sw, y1 = (pb.y - 0.5f * pb.w) * sh;
                float x2 = (pb.x + 0.5f * pb.z) * sw, y2 = (pb.y + 0.5f * pb.w) * sh;
                out[base] = score;
                out[BQ * 5 + base] = 1.f;
                float4 ob;
                ob.x = truncf(x1); ob.y = truncf(y1);
                ob.z = truncf(x2); ob.w = truncf(y2);
                ((float4*)(out + BQ))[base] = ob;
            }
        }
    } else {
        // ---- Fallback (M > NS, ~never): self-contained sort + greedy + full
        //      epilogue (overwrites producers' zeros; ordered by acquire) ----
        unsigned long long* skeyF = (unsigned long long*)smem;
        unsigned char* ssupp = (unsigned char*)(smem + 16384);
        unsigned char* keepqF = (unsigned char*)(smem + 18432);
        for (int qq = tid; qq < QN; qq += 1024) {
            float2 l = ((const float2*)logits)[b * QN + qq];
            bool valid;
            skeyF[qq] = score_key(l, qq, &valid);
        }
        keepqF[tid] = 0; keepqF[tid + 1024] = 0;
        __syncthreads();
        for (int k = 2; k <= QN; k <<= 1)
            for (int j = k >> 1; j > 0; j >>= 1) {
                int i = ((tid & ~(j - 1)) << 1) | (tid & (j - 1));
                int p = i | j;
                bool up = ((i & k) == 0);
                unsigned long long a = skeyF[i], c2 = skeyF[p];
                if ((a > c2) == up) { skeyF[i] = c2; skeyF[p] = a; }
                __syncthreads();
            }
        for (int s = tid; s < M; s += 1024) ssupp[s] = 0;
        __syncthreads();
        for (int i = 0; i < M; ++i) {
            __syncthreads();
            if (ssupp[i]) continue;
            int ia = (unsigned short)(unsigned)skeyF[i];
            float4 pa = ((const float4*)pboxes)[b * QN + ia];
            float ax1 = (pa.x - 0.5f * pa.z) * sw, ay1 = (pa.y - 0.5f * pa.w) * sh;
            float ax2 = (pa.x + 0.5f * pa.z) * sw, ay2 = (pa.y + 0.5f * pa.w) * sh;
            float areaA = fmaxf(ax2 - ax1, 0.f) * fmaxf(ay2 - ay1, 0.f);
            for (int jj = i + 1 + tid; jj < M; jj += 1024) {
                int jb = (unsigned short)(unsigned)skeyF[jj];
                float4 pq = ((const float4*)pboxes)[b * QN + jb];
                float bx1 = (pq.x - 0.5f * pq.z) * sw, by1 = (pq.y - 0.5f * pq.w) * sh;
                float bx2 = (pq.x + 0.5f * pq.z) * sw, by2 = (pq.y + 0.5f * pq.w) * sh;
                float ltx = fmaxf(ax1, bx1), lty = fmaxf(ay1, by1);
                float rbx = fminf(ax2, bx2), rby = fminf(ay2, by2);
                float wx = fmaxf(rbx - ltx, 0.f), wy = fmaxf(rby - lty, 0.f);
                float inter = wx * wy;
                float areaB = fmaxf(bx2 - bx1, 0.f) * fmaxf(by2 - by1, 0.f);
                float uni = areaA + areaB - inter;
                if (inter / fmaxf(uni, 1e-9f) > 0.5f) ssupp[jj] = 1;
            }
        }
        __syncthreads();
        for (int s = tid; s < M; s += 1024)
            if (!ssupp[s]) keepqF[(unsigned short)(unsigned)skeyF[s]] = 1;
        __syncthreads();
#pragma unroll
        for (int qq = 0; qq < 2; ++qq) {
            int q = tid + qq * 1024;
            int base = b * QN + q;
            float2 l = ((const float2*)logits)[base];
            float e = expf(fminf(l.x, l.y) - fmaxf(l.x, l.y));
            float score = 1.0f / (1.0f + e);
            float4 pb = ((const float4*)pboxes)[base];
            float x1 = (pb.x - 0.5f * pb.z) * sw, y1 = (pb.y - 0.5f * pb.w) * sh;
            float x2 = (pb.x + 0.5f * pb.z) * sw, y2 = (pb.y + 0.5f * pb.w) * sh;
            int kp = keepqF[q];
            out[base] = kp ? score : 0.f;
            out[BQ * 5 + base] = kp ? 1.f : 0.f;
            float4 ob;
            ob.x = kp ? truncf(x1) : 0.f;
            ob.y = kp ? truncf(y1) : 0.f;
            ob.z = kp ? truncf(x2) : 0.f;
            ob.w = kp ? truncf(y2) : 0.f;
            ((float4*)(out + BQ))[base] = ob;
        }
    }
}

extern "C" void kernel_launch(void* const* d_in, const int* in_sizes, int n_in,
                              void* d_out, int out_size, void* d_ws, size_t ws_size,
                              hipStream_t stream) {
    const float* logits = (const float*)d_in[0];
    const float* pboxes = (const float*)d_in[1];
    const int*   img_h  = (const int*)d_in[2];
    const int*   img_w  = (const int*)d_in[3];
    float* out = (float*)d_out;
    const int B = in_sizes[0] / (QN * 2);   // 16

    char* ws = (char*)d_ws;                 // footprint 1,115,136 B (< proven 1.148MB)
    unsigned* wflag = (unsigned*)(ws + 0);
    unsigned* wmat  = (unsigned*)(ws + 1024);

    kfused<<<dim3(B * NSLICE), dim3(1024), 0, stream>>>(logits, pboxes, img_h, img_w,
                                                        wflag, wmat, out, B);
}